// Round 1
// 297.581 us; speedup vs baseline: 1.0020x; 1.0020x over previous
//
#include <hip/hip_runtime.h>
#include <cstdint>
#include <cstddef>

// Quantized linear (Brevitas-style int8 per-tensor symmetric).
//   x [N=32768, K=1024] f32, w [M=1024, K=1024] f32, bias [M] f32.
//   sx = max|x|/127, sw = max|w|/127; qx = clip(rne(x/sx)) int8, qw likewise
//   out[n,m] = (sum_k qx[n,k]*qw[m,k]) * sx*sw + bias[m]   (f32)
//
// ws layout:
//   [0..7]      2 floats: final amax_x, amax_w  (written by quant kernel)
//   [64..]      544 float per-block partial maxes (512 for x, 32 for w)
//   [4096..]    qx (N*K int8), then qw (M*K int8)

typedef int v4i __attribute__((ext_vector_type(4)));

#define QMAXF 127.0f
#define KDIM 1024
#define MDIM 1024
#define NBX 512   // absmax blocks for x
#define NBW 32    // absmax blocks for w

// ---------------- pass 1: per-block partial |max| (no atomics, no init) ----
__global__ __launch_bounds__(256) void absmax_partial(
    const float4* __restrict__ x, int nx4,
    const float4* __restrict__ w, int nw4,
    float* __restrict__ partials) {
  const int b = blockIdx.x;
  const bool isw = (b >= NBX);
  const float4* __restrict__ p = isw ? w : x;
  const int n4 = isw ? nw4 : nx4;
  const int nb = isw ? NBW : NBX;
  const int bb = isw ? (b - NBX) : b;
  const int stride = nb * 256;

  float m0 = 0.f, m1 = 0.f, m2 = 0.f, m3 = 0.f;
  int i = bb * 256 + threadIdx.x;
  for (; i + 3 * stride < n4; i += 4 * stride) {
    float4 v0 = p[i], v1 = p[i + stride], v2 = p[i + 2 * stride],
           v3 = p[i + 3 * stride];
    m0 = fmaxf(m0, fmaxf(fmaxf(fabsf(v0.x), fabsf(v0.y)),
                         fmaxf(fabsf(v0.z), fabsf(v0.w))));
    m1 = fmaxf(m1, fmaxf(fmaxf(fabsf(v1.x), fabsf(v1.y)),
                         fmaxf(fabsf(v1.z), fabsf(v1.w))));
    m2 = fmaxf(m2, fmaxf(fmaxf(fabsf(v2.x), fabsf(v2.y)),
                         fmaxf(fabsf(v2.z), fabsf(v2.w))));
    m3 = fmaxf(m3, fmaxf(fmaxf(fabsf(v3.x), fabsf(v3.y)),
                         fmaxf(fabsf(v3.z), fabsf(v3.w))));
  }
  for (; i < n4; i += stride) {
    float4 v = p[i];
    m0 = fmaxf(m0, fmaxf(fmaxf(fabsf(v.x), fabsf(v.y)),
                         fmaxf(fabsf(v.z), fabsf(v.w))));
  }
  float m = fmaxf(fmaxf(m0, m1), fmaxf(m2, m3));
  for (int off = 32; off; off >>= 1) m = fmaxf(m, __shfl_down(m, off, 64));
  __shared__ float wm[4];
  const int lane = threadIdx.x & 63, wid = threadIdx.x >> 6;
  if (lane == 0) wm[wid] = m;
  __syncthreads();
  if (threadIdx.x == 0)
    partials[b] = fmaxf(fmaxf(wm[0], wm[1]), fmaxf(wm[2], wm[3]));
}

// ---------------- pass 2: reduce partials + quantize (16 elems/iter) -------
__global__ __launch_bounds__(256) void quant2(
    const float4* __restrict__ x, int nx16,
    const float4* __restrict__ w, int nw16,
    const float* __restrict__ partials,
    v4i* __restrict__ qx, v4i* __restrict__ qw,
    float* __restrict__ amax_out) {
  const int sel = blockIdx.y;
  // reduce this tensor's partials (identical result in every block)
  const float* pp = partials + (sel ? NBX : 0);
  const int np = sel ? NBW : NBX;
  float m = 0.f;
  for (int i = threadIdx.x; i < np; i += 256) m = fmaxf(m, pp[i]);
  for (int off = 32; off; off >>= 1) m = fmaxf(m, __shfl_down(m, off, 64));
  __shared__ float wm[4];
  __shared__ float bmax;
  const int lane = threadIdx.x & 63, wid = threadIdx.x >> 6;
  if (lane == 0) wm[wid] = m;
  __syncthreads();
  if (threadIdx.x == 0) {
    float bm = fmaxf(fmaxf(wm[0], wm[1]), fmaxf(wm[2], wm[3]));
    bmax = bm;
    if (blockIdx.x == 0) amax_out[sel] = bm;  // publish for GEMM epilogue
  }
  __syncthreads();
  const float amax = bmax;
  const float r = QMAXF / amax;

  const float4* __restrict__ p = sel ? w : x;
  const int n16 = sel ? nw16 : nx16;
  v4i* __restrict__ q = sel ? qw : qx;

  for (int i = blockIdx.x * 256 + threadIdx.x; i < n16;
       i += gridDim.x * 256) {
    float4 v0 = p[4 * i], v1 = p[4 * i + 1], v2 = p[4 * i + 2],
           v3 = p[4 * i + 3];
    v4i o;
#define QPK(V)                                                         \
  ((((int)fminf(fmaxf(rintf((V).x * r), -QMAXF), QMAXF)) & 255) |      \
   ((((int)fminf(fmaxf(rintf((V).y * r), -QMAXF), QMAXF)) & 255) << 8) | \
   ((((int)fminf(fmaxf(rintf((V).z * r), -QMAXF), QMAXF)) & 255) << 16) | \
   ((((int)fminf(fmaxf(rintf((V).w * r), -QMAXF), QMAXF)) & 255) << 24))
    o[0] = QPK(v0);
    o[1] = QPK(v1);
    o[2] = QPK(v2);
    o[3] = QPK(v3);
#undef QPK
    q[i] = o;
  }
}

// ---------------- pass 3: i8 MFMA GEMM, 256x256 tile, 8-phase schedule -----
// Port of the verified 256^2 8-phase template (T2 swizzle + T3/T4 counted
// vmcnt + T5 setprio) to int8, BK=128 (128 B rows -> same seg-XOR swizzle).
// 8 waves (4 N-quadrants x 2 M-halves), per-wave 64x128 output (4x8 v4i acc).
// Double-buffered LDS 128 KiB, 1 block/CU, raw s_barrier (no vmcnt drain).
//
// Half-tiles are the strided row-sets each quadrant consumes:
//   Ah0 = rows with (r%64)<32  (a-frags i in {0,1} for every wave)
//   Ah1 = rows with (r%64)>=32
//   Bh0 = rows with (r%128)<64 (b-frags j in {0..3})
//   Bh1 = rows with (r%128)>=64
// Per group (one K-tile) issue order: Ah0,Bh0,Bh1,Ah1 of tile t+1, one per
// phase.  vmcnt ledger (2 loads per half-tile stage):
//   end q3: outstanding 8  -> vmcnt(4): Ah0(t),Bh0(t) done for q0 reads
//   end q0: outstanding 6  -> vmcnt(4): Bh1(t) done for q1
//   end q1: outstanding 6  -> vmcnt(4): Ah1(t) done for q2
//   end q2: no wait (q3 needs nothing new).  Tail group: 4 -> 2 -> 0.

__device__ __forceinline__ void ld_lds16(const void* g, void* l) {
  __builtin_amdgcn_global_load_lds(
      (__attribute__((address_space(1))) void*)(void*)g,
      (__attribute__((address_space(3))) void*)l, 16, 0, 0);
}

#define SBAR() asm volatile("s_barrier" ::: "memory")
#define WAITV(n) asm volatile("s_waitcnt vmcnt(" #n ")" ::: "memory")

#define BK 128
#define BMT 256
#define BNT 256

__global__ __launch_bounds__(512, 2) void gemm_i8(
    const char* __restrict__ qx, const char* __restrict__ qw,
    const float* __restrict__ bias, const float* __restrict__ amax,
    float* __restrict__ out) {
  __shared__ __align__(16) char smA[2][BNT * BK];
  __shared__ __align__(16) char smB[2][BMT * BK];

  const int tid = threadIdx.x;
  const int wave = tid >> 6;
  const int lane = tid & 63;

  // XCD-bijective block swizzle: 512 blocks, 8 XCDs, 64 blocks per XCD.
  // Each XCD gets one bm (w-panel 256 KB stays L2-resident).
  const int p = blockIdx.x;
  const int lb = (p & 7) * 64 + (p >> 3);
  const int bm = lb >> 7;   // 0..3
  const int bn = lb & 127;  // 0..127

  const int wn = wave >> 1;  // 0..3: N quadrant (64 rows)
  const int wm = wave & 1;   // 0..1: M half (128 rows)

  const char* __restrict__ xb = qx + (size_t)bn * BNT * KDIM;
  const char* __restrict__ wb = qw + (size_t)bm * BMT * KDIM;

  const int lrow = lane >> 3;         // row within an 8-row staging slab
  const int sgx = (lane & 7) ^ lrow;  // swizzled source segment
  const int gcol = sgx * 16;

  v4i acc[4][8] = {};

  // stage one A half-tile (128 rows: blocks of 32 at r%64 == half*32)
#define STAGE_A(bufc, kb, half) do {                                        \
    _Pragma("unroll") for (int c = 0; c < 2; ++c) {                         \
      const int sg = wave * 2 + c;                                          \
      const int rb = (sg >> 2) * 64 + (half) * 32 + (sg & 3) * 8;           \
      ld_lds16(xb + (size_t)(rb + lrow) * KDIM + (kb) + gcol,               \
               &smA[bufc][rb * BK]);                                        \
    }                                                                       \
  } while (0)
  // stage one B half-tile (128 rows: blocks of 64 at r%128 == half*64)
#define STAGE_B(bufc, kb, half) do {                                        \
    _Pragma("unroll") for (int c = 0; c < 2; ++c) {                         \
      const int sg = wave * 2 + c;                                          \
      const int rb = (sg >> 3) * 128 + (half) * 64 + (sg & 7) * 8;          \
      ld_lds16(wb + (size_t)(rb + lrow) * KDIM + (kb) + gcol,               \
               &smB[bufc][rb * BK]);                                        \
    }                                                                       \
  } while (0)

  // one phase: ds-load quadrant frags || stage next half-tile; barrier;
  // MFMA cluster under setprio; counted vmcnt; barrier.
#define PHASE(bufc, ih, jh, STG, WT) do {                                   \
    v4i a_[2][2], b_[2][4];                                                 \
    _Pragma("unroll") for (int ks = 0; ks < 2; ++ks) {                      \
      const int sw = ((ks * 4 + (lane >> 4)) * 16) ^ ((lane & 7) * 16);     \
      _Pragma("unroll") for (int i = 0; i < 2; ++i) {                       \
        const int r = wn * 64 + (ih) * 32 + i * 16 + (lane & 15);           \
        a_[ks][i] = *(const v4i*)(&smA[bufc][r * BK + sw]);                 \
      }                                                                     \
      _Pragma("unroll") for (int j = 0; j < 4; ++j) {                       \
        const int r = wm * 128 + (jh) * 64 + j * 16 + (lane & 15);          \
        b_[ks][j] = *(const v4i*)(&smB[bufc][r * BK + sw]);                 \
      }                                                                     \
    }                                                                       \
    STG;                                                                    \
    SBAR();                                                                 \
    __builtin_amdgcn_s_setprio(1);                                          \
    _Pragma("unroll") for (int ks = 0; ks < 2; ++ks)                        \
      _Pragma("unroll") for (int i = 0; i < 2; ++i)                         \
        _Pragma("unroll") for (int j = 0; j < 4; ++j)                       \
          acc[(ih) * 2 + i][(jh) * 4 + j] =                                 \
              __builtin_amdgcn_mfma_i32_16x16x64_i8(                        \
                  a_[ks][i], b_[ks][j], acc[(ih) * 2 + i][(jh) * 4 + j],    \
                  0, 0, 0);                                                 \
    __builtin_amdgcn_s_setprio(0);                                          \
    WT;                                                                     \
    SBAR();                                                                 \
  } while (0)

  // one steady K-group: 4 quadrant phases, staging tile t+1 into buf^1
#define GROUP(bufc, kb1)                                                    \
    PHASE(bufc, 0, 0, STAGE_A((bufc) ^ 1, kb1, 0), WAITV(4));               \
    PHASE(bufc, 0, 1, STAGE_B((bufc) ^ 1, kb1, 0), WAITV(4));               \
    PHASE(bufc, 1, 0, STAGE_B((bufc) ^ 1, kb1, 1), (void)0);                \
    PHASE(bufc, 1, 1, STAGE_A((bufc) ^ 1, kb1, 1), WAITV(4));

  // prologue: stage tile 0 (issue order must match the ledger)
  STAGE_A(0, 0, 0);
  STAGE_B(0, 0, 0);
  STAGE_B(0, 0, 1);
  STAGE_A(0, 0, 1);
  WAITV(4);  // Ah0(0),Bh0(0) landed; Bh1,Ah1 still in flight
  SBAR();

  GROUP(0, 1 * BK);
  GROUP(1, 2 * BK);
  GROUP(0, 3 * BK);
  GROUP(1, 4 * BK);
  GROUP(0, 5 * BK);
  GROUP(1, 6 * BK);
  GROUP(0, 7 * BK);
  // tail group: tile 7 in buf 1, nothing left to stage; drain 4 -> 2 -> 0
  PHASE(1, 0, 0, (void)0, WAITV(2));
  PHASE(1, 0, 1, (void)0, WAITV(0));
  PHASE(1, 1, 0, (void)0, (void)0);
  PHASE(1, 1, 1, (void)0, (void)0);

#undef GROUP
#undef PHASE
#undef STAGE_A
#undef STAGE_B

  // epilogue: C/D layout col=lane&15 (m), row=(lane>>4)*4+reg (n)
  const float sfac = (amax[0] / QMAXF) * (amax[1] / QMAXF);
  const int mcol = bm * BMT + wm * 128 + (lane & 15);
  const int nb0 = bn * BNT + wn * 64 + ((lane >> 4) << 2);
  float bv[8];
#pragma unroll
  for (int j = 0; j < 8; ++j) bv[j] = bias[mcol + j * 16];
#pragma unroll
  for (int i = 0; i < 4; ++i) {
#pragma unroll
    for (int r = 0; r < 4; ++r) {
      const int n = nb0 + i * 16 + r;
      float* orow = out + (size_t)n * MDIM + mcol;
#pragma unroll
      for (int j = 0; j < 8; ++j)
        orow[j * 16] = (float)acc[i][j][r] * sfac + bv[j];
    }
  }
}

extern "C" void kernel_launch(void* const* d_in, const int* in_sizes, int n_in,
                              void* d_out, int out_size, void* d_ws, size_t ws_size,
                              hipStream_t stream) {
  const float* x = (const float*)d_in[0];
  const float* w = (const float*)d_in[1];
  const float* bias = (const float*)d_in[2];
  float* out = (float*)d_out;

  const int NX = in_sizes[0];  // N*K = 33554432
  const int NW = in_sizes[1];  // M*K = 1048576
  const int N = NX / KDIM;     // 32768

  float* amax = (float*)d_ws;
  float* partials = (float*)((char*)d_ws + 64);
  char* qx = (char*)d_ws + 4096;
  char* qw = qx + (size_t)NX;

  absmax_partial<<<NBX + NBW, 256, 0, stream>>>(
      (const float4*)x, NX / 4, (const float4*)w, NW / 4, partials);

  dim3 qgrid(1024, 2);
  quant2<<<qgrid, 256, 0, stream>>>((const float4*)x, NX / 16,
                                    (const float4*)w, NW / 16, partials,
                                    (v4i*)qx, (v4i*)qw, amax);

  // 512 blocks = (M/256=4) x (N/256=128), XCD-chunked inside the kernel
  gemm_i8<<<dim3(512), 512, 0, stream>>>(qx, qw, bias, amax, out);
}

// Round 2
// 292.589 us; speedup vs baseline: 1.0190x; 1.0171x over previous
//
#include <hip/hip_runtime.h>
#include <cstdint>
#include <cstddef>

// Quantized linear (Brevitas-style int8 per-tensor symmetric).
//   x [N=32768, K=1024] f32, w [M=1024, K=1024] f32, bias [M] f32.
//   sx = max|x|/127, sw = max|w|/127; qx = clip(rne(x/sx)) int8, qw likewise
//   out[n,m] = (sum_k qx[n,k]*qw[m,k]) * sx*sw + bias[m]   (f32)
//
// ws layout:
//   [0..7]      2 floats: final amax_x, amax_w  (written by quant kernel)
//   [64..]      544 float per-block partial maxes (512 for x, 32 for w)
//   [4096..]    qx (N*K int8), then qw (M*K int8)

typedef int v4i __attribute__((ext_vector_type(4)));

#define QMAXF 127.0f
#define KDIM 1024
#define MDIM 1024
#define NBX 512   // absmax blocks for x
#define NBW 32    // absmax blocks for w

// ---------------- pass 1: per-block partial |max| (no atomics, no init) ----
__global__ __launch_bounds__(256) void absmax_partial(
    const float4* __restrict__ x, int nx4,
    const float4* __restrict__ w, int nw4,
    float* __restrict__ partials) {
  const int b = blockIdx.x;
  const bool isw = (b >= NBX);
  const float4* __restrict__ p = isw ? w : x;
  const int n4 = isw ? nw4 : nx4;
  const int nb = isw ? NBW : NBX;
  const int bb = isw ? (b - NBX) : b;
  const int stride = nb * 256;

  float m0 = 0.f, m1 = 0.f, m2 = 0.f, m3 = 0.f;
  int i = bb * 256 + threadIdx.x;
  for (; i + 3 * stride < n4; i += 4 * stride) {
    float4 v0 = p[i], v1 = p[i + stride], v2 = p[i + 2 * stride],
           v3 = p[i + 3 * stride];
    m0 = fmaxf(m0, fmaxf(fmaxf(fabsf(v0.x), fabsf(v0.y)),
                         fmaxf(fabsf(v0.z), fabsf(v0.w))));
    m1 = fmaxf(m1, fmaxf(fmaxf(fabsf(v1.x), fabsf(v1.y)),
                         fmaxf(fabsf(v1.z), fabsf(v1.w))));
    m2 = fmaxf(m2, fmaxf(fmaxf(fabsf(v2.x), fabsf(v2.y)),
                         fmaxf(fabsf(v2.z), fabsf(v2.w))));
    m3 = fmaxf(m3, fmaxf(fmaxf(fabsf(v3.x), fabsf(v3.y)),
                         fmaxf(fabsf(v3.z), fabsf(v3.w))));
  }
  for (; i < n4; i += stride) {
    float4 v = p[i];
    m0 = fmaxf(m0, fmaxf(fmaxf(fabsf(v.x), fabsf(v.y)),
                         fmaxf(fabsf(v.z), fabsf(v.w))));
  }
  float m = fmaxf(fmaxf(m0, m1), fmaxf(m2, m3));
  for (int off = 32; off; off >>= 1) m = fmaxf(m, __shfl_down(m, off, 64));
  __shared__ float wm[4];
  const int lane = threadIdx.x & 63, wid = threadIdx.x >> 6;
  if (lane == 0) wm[wid] = m;
  __syncthreads();
  if (threadIdx.x == 0)
    partials[b] = fmaxf(fmaxf(wm[0], wm[1]), fmaxf(wm[2], wm[3]));
}

// ---------------- pass 2: reduce partials + quantize (16 elems/iter) -------
__global__ __launch_bounds__(256) void quant2(
    const float4* __restrict__ x, int nx16,
    const float4* __restrict__ w, int nw16,
    const float* __restrict__ partials,
    v4i* __restrict__ qx, v4i* __restrict__ qw,
    float* __restrict__ amax_out) {
  const int sel = blockIdx.y;
  // reduce this tensor's partials (identical result in every block)
  const float* pp = partials + (sel ? NBX : 0);
  const int np = sel ? NBW : NBX;
  float m = 0.f;
  for (int i = threadIdx.x; i < np; i += 256) m = fmaxf(m, pp[i]);
  for (int off = 32; off; off >>= 1) m = fmaxf(m, __shfl_down(m, off, 64));
  __shared__ float wm[4];
  __shared__ float bmax;
  const int lane = threadIdx.x & 63, wid = threadIdx.x >> 6;
  if (lane == 0) wm[wid] = m;
  __syncthreads();
  if (threadIdx.x == 0) {
    float bm = fmaxf(fmaxf(wm[0], wm[1]), fmaxf(wm[2], wm[3]));
    bmax = bm;
    if (blockIdx.x == 0) amax_out[sel] = bm;  // publish for GEMM epilogue
  }
  __syncthreads();
  const float amax = bmax;
  const float r = QMAXF / amax;

  const float4* __restrict__ p = sel ? w : x;
  const int n16 = sel ? nw16 : nx16;
  v4i* __restrict__ q = sel ? qw : qx;

  for (int i = blockIdx.x * 256 + threadIdx.x; i < n16;
       i += gridDim.x * 256) {
    float4 v0 = p[4 * i], v1 = p[4 * i + 1], v2 = p[4 * i + 2],
           v3 = p[4 * i + 3];
    v4i o;
#define QPK(V)                                                         \
  ((((int)fminf(fmaxf(rintf((V).x * r), -QMAXF), QMAXF)) & 255) |      \
   ((((int)fminf(fmaxf(rintf((V).y * r), -QMAXF), QMAXF)) & 255) << 8) | \
   ((((int)fminf(fmaxf(rintf((V).z * r), -QMAXF), QMAXF)) & 255) << 16) | \
   ((((int)fminf(fmaxf(rintf((V).w * r), -QMAXF), QMAXF)) & 255) << 24))
    o[0] = QPK(v0);
    o[1] = QPK(v1);
    o[2] = QPK(v2);
    o[3] = QPK(v3);
#undef QPK
    q[i] = o;
  }
}

// ---------------- pass 3: i8 MFMA GEMM, 256x256 tile, 8-phase schedule -----
// Template-faithful port (single barrier per phase, counted vmcnt BEFORE the
// barrier — R1 had a second post-MFMA barrier that forced wave lockstep and
// capped MfmaUtil at 16%).
//
// Phase = {ds-read quadrant frags ; issue 1 half-tile stage ; counted vmcnt ;
//          s_barrier ; setprio(1) 16xMFMA setprio(0)}.
// Reads of phase p overlap other waves' MFMA of phase p-1 (this is the
// pipeline). Safety across the buffer swap: each half-tile's stage-write
// trails its last reader's lgkm-drain by >=1 full barrier:
//   A0'@q0 vs last read q1(t-1); B0'@q1 vs q2(t-1);
//   B1'@q2 vs q3(t-1); A1'@q3 vs q3(t-1).   (reads pair: q0=A0B0, q1=A0B1,
//   q2=A1B0, q3=A1B1; stage order A0,B0,B1,A1 — engineered disjointness.)
//
// Per-wave vmcnt ledger (2 loads per half-tile stage), waits BEFORE barrier:
//   q0: outstanding 6 -> vmcnt(4): B1(t) done for q1 reads
//   q1: outstanding 6 -> vmcnt(4): A1(t) done for q2 reads
//   q2: no wait
//   q3: outstanding 8 -> vmcnt(4): A0(t+1),B0(t+1) done for next q0 reads
// Tail (no staging): q0 vmcnt(2) [B1(t7)], q1 vmcnt(0) [A1(t7)], then none.

__device__ __forceinline__ void ld_lds16(const void* g, void* l) {
  __builtin_amdgcn_global_load_lds(
      (__attribute__((address_space(1))) void*)(void*)g,
      (__attribute__((address_space(3))) void*)l, 16, 0, 0);
}

#define SBAR() asm volatile("s_barrier" ::: "memory")
#define WAITV(n) asm volatile("s_waitcnt vmcnt(" #n ")" ::: "memory")

#define BK 128
#define BMT 256
#define BNT 256

__global__ __launch_bounds__(512, 2) void gemm_i8(
    const char* __restrict__ qx, const char* __restrict__ qw,
    const float* __restrict__ bias, const float* __restrict__ amax,
    float* __restrict__ out) {
  __shared__ __align__(16) char smA[2][BNT * BK];
  __shared__ __align__(16) char smB[2][BMT * BK];

  const int tid = threadIdx.x;
  const int wave = tid >> 6;
  const int lane = tid & 63;

  // XCD-bijective block swizzle: 512 blocks, 8 XCDs, 64 blocks per XCD.
  // Each XCD gets one bm (w-panel 256 KB stays L2-resident).
  const int p = blockIdx.x;
  const int lb = (p & 7) * 64 + (p >> 3);
  const int bm = lb >> 7;   // 0..3
  const int bn = lb & 127;  // 0..127

  const int wn = wave >> 1;  // 0..3: N quadrant (64 rows)
  const int wm = wave & 1;   // 0..1: M half (128 rows)

  const char* __restrict__ xb = qx + (size_t)bn * BNT * KDIM;
  const char* __restrict__ wb = qw + (size_t)bm * BMT * KDIM;

  const int lrow = lane >> 3;         // row within an 8-row staging slab
  const int sgx = (lane & 7) ^ lrow;  // swizzled source segment
  const int gcol = sgx * 16;

  v4i acc[4][8] = {};

  // stage one A half-tile (128 rows: blocks of 32 at r%64 == half*32)
#define STAGE_A(bufc, kb, half) do {                                        \
    _Pragma("unroll") for (int c = 0; c < 2; ++c) {                         \
      const int sg = wave * 2 + c;                                          \
      const int rb = (sg >> 2) * 64 + (half) * 32 + (sg & 3) * 8;           \
      ld_lds16(xb + (size_t)(rb + lrow) * KDIM + (kb) + gcol,               \
               &smA[bufc][rb * BK]);                                        \
    }                                                                       \
  } while (0)
  // stage one B half-tile (128 rows: blocks of 64 at r%128 == half*64)
#define STAGE_B(bufc, kb, half) do {                                        \
    _Pragma("unroll") for (int c = 0; c < 2; ++c) {                         \
      const int sg = wave * 2 + c;                                          \
      const int rb = (sg >> 3) * 128 + (half) * 64 + (sg & 7) * 8;          \
      ld_lds16(wb + (size_t)(rb + lrow) * KDIM + (kb) + gcol,               \
               &smB[bufc][rb * BK]);                                        \
    }                                                                       \
  } while (0)

  // one phase: ds-load quadrant frags || stage next half-tile; counted
  // vmcnt; ONE barrier; MFMA cluster under setprio.  No post-MFMA barrier:
  // next phase's reads overlap other waves' MFMA.
#define PHASE(bufc, ih, jh, STG, WT) do {                                   \
    v4i a_[2][2], b_[2][4];                                                 \
    _Pragma("unroll") for (int ks = 0; ks < 2; ++ks) {                      \
      const int sw = ((ks * 4 + (lane >> 4)) * 16) ^ ((lane & 7) * 16);     \
      _Pragma("unroll") for (int i = 0; i < 2; ++i) {                       \
        const int r = wn * 64 + (ih) * 32 + i * 16 + (lane & 15);           \
        a_[ks][i] = *(const v4i*)(&smA[bufc][r * BK + sw]);                 \
      }                                                                     \
      _Pragma("unroll") for (int j = 0; j < 4; ++j) {                       \
        const int r = wm * 128 + (jh) * 64 + j * 16 + (lane & 15);          \
        b_[ks][j] = *(const v4i*)(&smB[bufc][r * BK + sw]);                 \
      }                                                                     \
    }                                                                       \
    STG;                                                                    \
    WT;                                                                     \
    SBAR();                                                                 \
    __builtin_amdgcn_s_setprio(1);                                          \
    _Pragma("unroll") for (int ks = 0; ks < 2; ++ks)                        \
      _Pragma("unroll") for (int i = 0; i < 2; ++i)                         \
        _Pragma("unroll") for (int j = 0; j < 4; ++j)                       \
          acc[(ih) * 2 + i][(jh) * 4 + j] =                                 \
              __builtin_amdgcn_mfma_i32_16x16x64_i8(                        \
                  a_[ks][i], b_[ks][j], acc[(ih) * 2 + i][(jh) * 4 + j],    \
                  0, 0, 0);                                                 \
    __builtin_amdgcn_s_setprio(0);                                          \
  } while (0)

  // one steady K-group: 4 quadrant phases, staging tile t+1 into buf^1
#define GROUP(bufc, kb1)                                                    \
    PHASE(bufc, 0, 0, STAGE_A((bufc) ^ 1, kb1, 0), WAITV(4));               \
    PHASE(bufc, 0, 1, STAGE_B((bufc) ^ 1, kb1, 0), WAITV(4));               \
    PHASE(bufc, 1, 0, STAGE_B((bufc) ^ 1, kb1, 1), (void)0);                \
    PHASE(bufc, 1, 1, STAGE_A((bufc) ^ 1, kb1, 1), WAITV(4));

  // prologue: stage tile 0 (issue order must match the ledger)
  STAGE_A(0, 0, 0);
  STAGE_B(0, 0, 0);
  STAGE_B(0, 0, 1);
  STAGE_A(0, 0, 1);
  WAITV(4);  // Ah0(0),Bh0(0) landed; Bh1,Ah1 still in flight
  SBAR();

  GROUP(0, 1 * BK);
  GROUP(1, 2 * BK);
  GROUP(0, 3 * BK);
  GROUP(1, 4 * BK);
  GROUP(0, 5 * BK);
  GROUP(1, 6 * BK);
  GROUP(0, 7 * BK);
  // tail group: tile 7 in buf 1, nothing left to stage; drain 4 -> 2 -> 0
  PHASE(1, 0, 0, (void)0, WAITV(2));
  PHASE(1, 0, 1, (void)0, WAITV(0));
  PHASE(1, 1, 0, (void)0, (void)0);
  PHASE(1, 1, 1, (void)0, (void)0);

#undef GROUP
#undef PHASE
#undef STAGE_A
#undef STAGE_B

  // epilogue: C/D layout col=lane&15 (m), row=(lane>>4)*4+reg (n)
  const float sfac = (amax[0] / QMAXF) * (amax[1] / QMAXF);
  const int mcol = bm * BMT + wm * 128 + (lane & 15);
  const int nb0 = bn * BNT + wn * 64 + ((lane >> 4) << 2);
  float bv[8];
#pragma unroll
  for (int j = 0; j < 8; ++j) bv[j] = bias[mcol + j * 16];
#pragma unroll
  for (int i = 0; i < 4; ++i) {
#pragma unroll
    for (int r = 0; r < 4; ++r) {
      const int n = nb0 + i * 16 + r;
      float* orow = out + (size_t)n * MDIM + mcol;
#pragma unroll
      for (int j = 0; j < 8; ++j)
        orow[j * 16] = (float)acc[i][j][r] * sfac + bv[j];
    }
  }
}

extern "C" void kernel_launch(void* const* d_in, const int* in_sizes, int n_in,
                              void* d_out, int out_size, void* d_ws, size_t ws_size,
                              hipStream_t stream) {
  const float* x = (const float*)d_in[0];
  const float* w = (const float*)d_in[1];
  const float* bias = (const float*)d_in[2];
  float* out = (float*)d_out;

  const int NX = in_sizes[0];  // N*K = 33554432
  const int NW = in_sizes[1];  // M*K = 1048576
  const int N = NX / KDIM;     // 32768

  float* amax = (float*)d_ws;
  float* partials = (float*)((char*)d_ws + 64);
  char* qx = (char*)d_ws + 4096;
  char* qw = qx + (size_t)NX;

  absmax_partial<<<NBX + NBW, 256, 0, stream>>>(
      (const float4*)x, NX / 4, (const float4*)w, NW / 4, partials);

  dim3 qgrid(1024, 2);
  quant2<<<qgrid, 256, 0, stream>>>((const float4*)x, NX / 16,
                                    (const float4*)w, NW / 16, partials,
                                    (v4i*)qx, (v4i*)qw, amax);

  // 512 blocks = (M/256=4) x (N/256=128), XCD-chunked inside the kernel
  gemm_i8<<<dim3(512), 512, 0, stream>>>(qx, qw, bias, amax, out);
}